// Round 1
// baseline (648.060 us; speedup 1.0000x reference)
//
#include <hip/hip_runtime.h>

// ---------------------------------------------------------------------------
// FlexibleGraphSAGE: 3-layer SAGEConv (mean aggregation), fp32.
//   per layer: out = mean_agg(h) @ Wl^T + bl + h @ Wr^T   (+ReLU on layers 0,1)
// Strategy:
//   1) Build CSR (dst -> list of src) once per launch: deg count (int atomics),
//      single-block scan -> row_ptr/cursor/inv_deg, fill (atomic cursor).
//   2) Per layer: gather-aggregate (float4, 32 lanes per node), then one
//      fused GEMM over K=256 ([agg | h] @ [Wl | Wr]^T + bias, relu fused).
// ---------------------------------------------------------------------------

#define D_H 128

__global__ void count_deg_kernel(const int* __restrict__ dst, int* __restrict__ deg, int E) {
    int e = blockIdx.x * blockDim.x + threadIdx.x;
    if (e < E) atomicAdd(&deg[dst[e]], 1);
}

__global__ __launch_bounds__(1024) void scan_kernel(const int* __restrict__ deg,
                                                    int* __restrict__ row_ptr,
                                                    int* __restrict__ cursor,
                                                    float* __restrict__ inv_deg, int n) {
    __shared__ int partial[1024];
    int tid = threadIdx.x;
    int chunk = (n + 1023) >> 10;
    int start = tid * chunk;
    int end = min(start + chunk, n);
    int s = 0;
    for (int i = start; i < end; ++i) s += deg[i];
    partial[tid] = s;
    __syncthreads();
    for (int off = 1; off < 1024; off <<= 1) {
        int v = (tid >= off) ? partial[tid - off] : 0;
        __syncthreads();
        partial[tid] += v;
        __syncthreads();
    }
    int excl = (tid == 0) ? 0 : partial[tid - 1];
    for (int i = start; i < end; ++i) {
        row_ptr[i] = excl;
        cursor[i] = excl;
        int d = deg[i];
        inv_deg[i] = 1.0f / (float)max(d, 1);
        excl += d;
    }
    if (tid == 1023) row_ptr[n] = partial[1023];
}

__global__ void fill_csr_kernel(const int* __restrict__ src, const int* __restrict__ dst,
                                int* __restrict__ cursor, int* __restrict__ col, int E) {
    int e = blockIdx.x * blockDim.x + threadIdx.x;
    if (e < E) {
        int pos = atomicAdd(&cursor[dst[e]], 1);
        col[pos] = src[e];
    }
}

// agg[v] = inv_deg[v] * sum_{u in N(v)} h[u]   (h is [n, 128] fp32)
// 32 lanes per node (float4 per lane), 8 nodes per 256-thread block.
__global__ __launch_bounds__(256) void aggregate_kernel(const float* __restrict__ h,
                                                        const int* __restrict__ row_ptr,
                                                        const int* __restrict__ col,
                                                        const float* __restrict__ inv_deg,
                                                        float* __restrict__ agg, int n) {
    int group = threadIdx.x >> 5;
    int lane = threadIdx.x & 31;
    int node = blockIdx.x * 8 + group;
    if (node >= n) return;
    int beg = row_ptr[node];
    int end = row_ptr[node + 1];
    float4 acc = make_float4(0.f, 0.f, 0.f, 0.f);
    for (int e = beg; e < end; ++e) {
        int u = col[e];
        const float4 v = *(const float4*)&h[(size_t)u * D_H + (lane << 2)];
        acc.x += v.x; acc.y += v.y; acc.z += v.z; acc.w += v.w;
    }
    float s = inv_deg[node];
    float4 o = make_float4(acc.x * s, acc.y * s, acc.z * s, acc.w * s);
    *(float4*)&agg[(size_t)node * D_H + (lane << 2)] = o;
}

// out[n,o] = relu?( sum_k Xa[n,k]*Wa[o,k] + sum_k Xh[n,k]*Wh[o,k] + bias[o] )
// BM=BN=64, KC=64, 256 threads (16x16), 4x4 micro-tile, transposed LDS tiles
// (stride 68 floats keeps 16B alignment for ds_read_b128; 2-way bank alias only).
#define BM 64
#define BN 64
#define KC 64
__global__ __launch_bounds__(256) void gemm_sage_kernel(
        const float* __restrict__ Xa, const float* __restrict__ Xh,
        const float* __restrict__ Wa, const float* __restrict__ Wh,
        const float* __restrict__ bias, float* __restrict__ out,
        int N, int K1, int Do, int do_relu) {
    __shared__ float Xs[KC][BM + 4];
    __shared__ float Ws[KC][BN + 4];
    const int tid = threadIdx.x;
    const int tx = tid & 15, ty = tid >> 4;
    const int m0 = ty << 2, n0 = tx << 2;
    const int row0 = blockIdx.x * BM;
    const int col0 = blockIdx.y * BN;
    float acc[4][4] = {};

    for (int half = 0; half < 2; ++half) {
        const float* __restrict__ X = half ? Xh : Xa;
        const float* __restrict__ W = half ? Wh : Wa;
        for (int kc = 0; kc < K1; kc += KC) {
            __syncthreads();
            // stage X tile (BM x KC) transposed into Xs[k][m]
            #pragma unroll
            for (int q = tid; q < BM * KC / 4; q += 256) {
                int r = q >> 4;              // row within tile
                int k4 = (q & 15) << 2;      // k offset within chunk
                float4 v = make_float4(0.f, 0.f, 0.f, 0.f);
                int row = row0 + r;
                if (row < N) v = *(const float4*)&X[(size_t)row * K1 + kc + k4];
                Xs[k4 + 0][r] = v.x; Xs[k4 + 1][r] = v.y;
                Xs[k4 + 2][r] = v.z; Xs[k4 + 3][r] = v.w;
            }
            // stage W tile (BN x KC) transposed into Ws[k][n]
            #pragma unroll
            for (int q = tid; q < BN * KC / 4; q += 256) {
                int r = q >> 4;
                int k4 = (q & 15) << 2;
                float4 v = *(const float4*)&W[(size_t)(col0 + r) * K1 + kc + k4];
                Ws[k4 + 0][r] = v.x; Ws[k4 + 1][r] = v.y;
                Ws[k4 + 2][r] = v.z; Ws[k4 + 3][r] = v.w;
            }
            __syncthreads();
            #pragma unroll 8
            for (int k = 0; k < KC; ++k) {
                float4 a = *(const float4*)&Xs[k][m0];
                float4 b = *(const float4*)&Ws[k][n0];
                acc[0][0] += a.x * b.x; acc[0][1] += a.x * b.y; acc[0][2] += a.x * b.z; acc[0][3] += a.x * b.w;
                acc[1][0] += a.y * b.x; acc[1][1] += a.y * b.y; acc[1][2] += a.y * b.z; acc[1][3] += a.y * b.w;
                acc[2][0] += a.z * b.x; acc[2][1] += a.z * b.y; acc[2][2] += a.z * b.z; acc[2][3] += a.z * b.w;
                acc[3][0] += a.w * b.x; acc[3][1] += a.w * b.y; acc[3][2] += a.w * b.z; acc[3][3] += a.w * b.w;
            }
        }
    }

    // epilogue: bias + optional relu, float4 stores
    #pragma unroll
    for (int i = 0; i < 4; ++i) {
        int r = row0 + m0 + i;
        if (r >= N) continue;
        int c0 = col0 + n0;
        float4 v;
        v.x = acc[i][0] + bias[c0 + 0];
        v.y = acc[i][1] + bias[c0 + 1];
        v.z = acc[i][2] + bias[c0 + 2];
        v.w = acc[i][3] + bias[c0 + 3];
        if (do_relu) {
            v.x = fmaxf(v.x, 0.f); v.y = fmaxf(v.y, 0.f);
            v.z = fmaxf(v.z, 0.f); v.w = fmaxf(v.w, 0.f);
        }
        *(float4*)&out[(size_t)r * Do + c0] = v;
    }
}

extern "C" void kernel_launch(void* const* d_in, const int* in_sizes, int n_in,
                              void* d_out, int out_size, void* d_ws, size_t ws_size,
                              hipStream_t stream) {
    const float* x   = (const float*)d_in[0];
    const int*   edge = (const int*)d_in[1];   // int32 (JAX x64 disabled): [2, E]
    const float* Wl0 = (const float*)d_in[2];
    const float* bl0 = (const float*)d_in[3];
    const float* Wr0 = (const float*)d_in[4];
    const float* Wl1 = (const float*)d_in[5];
    const float* bl1 = (const float*)d_in[6];
    const float* Wr1 = (const float*)d_in[7];
    const float* Wl2 = (const float*)d_in[8];
    const float* bl2 = (const float*)d_in[9];
    const float* Wr2 = (const float*)d_in[10];
    float* out = (float*)d_out;

    const int N = in_sizes[0] / D_H;   // 50000
    const int E = in_sizes[1] / 2;     // 800000
    const int* src = edge;
    const int* dst = edge + E;

    char* w = (char*)d_ws;
    float* agg = (float*)w;      w += (size_t)N * D_H * 4;
    float* A   = (float*)w;      w += (size_t)N * D_H * 4;
    float* B   = (float*)w;      w += (size_t)N * D_H * 4;
    int* deg     = (int*)w;      w += (size_t)N * 4;
    int* row_ptr = (int*)w;      w += (size_t)(N + 1) * 4;
    int* cursor  = (int*)w;      w += (size_t)N * 4;
    float* inv_deg = (float*)w;  w += (size_t)N * 4;
    int* col     = (int*)w;      w += (size_t)E * 4;

    // ---- CSR build ----
    hipMemsetAsync(deg, 0, (size_t)N * 4, stream);
    count_deg_kernel<<<(E + 255) / 256, 256, 0, stream>>>(dst, deg, E);
    scan_kernel<<<1, 1024, 0, stream>>>(deg, row_ptr, cursor, inv_deg, N);
    fill_csr_kernel<<<(E + 255) / 256, 256, 0, stream>>>(src, dst, cursor, col, E);

    const int gx = (N + BM - 1) / BM;
    const int agg_grid = (N + 7) / 8;

    // ---- layer 0: x -> A (relu) ----
    aggregate_kernel<<<agg_grid, 256, 0, stream>>>(x, row_ptr, col, inv_deg, agg, N);
    gemm_sage_kernel<<<dim3(gx, 2), 256, 0, stream>>>(agg, x, Wl0, Wr0, bl0, A, N, 128, 128, 1);

    // ---- layer 1: A -> B (relu) ----
    aggregate_kernel<<<agg_grid, 256, 0, stream>>>(A, row_ptr, col, inv_deg, agg, N);
    gemm_sage_kernel<<<dim3(gx, 2), 256, 0, stream>>>(agg, A, Wl1, Wr1, bl1, B, N, 128, 128, 1);

    // ---- layer 2: B -> out (no relu) ----
    aggregate_kernel<<<agg_grid, 256, 0, stream>>>(B, row_ptr, col, inv_deg, agg, N);
    gemm_sage_kernel<<<dim3(gx, 1), 256, 0, stream>>>(agg, B, Wl2, Wr2, bl2, out, N, 128, 64, 0);
}

// Round 2
// 501.210 us; speedup vs baseline: 1.2930x; 1.2930x over previous
//
#include <hip/hip_runtime.h>

// ---------------------------------------------------------------------------
// FlexibleGraphSAGE: 3-layer SAGEConv (mean aggregation), fp32.
//   per layer: out = mean_agg(h) @ Wl^T + bl + h @ Wr^T   (+ReLU on layers 0,1)
// R1 changes vs R0:
//   - hierarchical 3-kernel scan (was: 135us single-block scan)
//   - aggregate: 1 wave per node, cooperative col load + shfl broadcast,
//     4-neighbor unrolled gathers (was: dependent-chain latency-bound)
// ---------------------------------------------------------------------------

#define D_H 128
#define NB_SCAN 256   // scan blocks; 256*256 = 65536 >= N

__global__ void count_deg_kernel(const int* __restrict__ dst, int* __restrict__ deg, int E) {
    int e = blockIdx.x * blockDim.x + threadIdx.x;
    if (e < E) atomicAdd(&deg[dst[e]], 1);
}

// S1: per-block sums of deg chunks
__global__ __launch_bounds__(256) void scan_reduce_kernel(const int* __restrict__ deg,
                                                          int* __restrict__ bsum, int n) {
    __shared__ int s[256];
    int t = threadIdx.x;
    int i = blockIdx.x * 256 + t;
    int v = (i < n) ? deg[i] : 0;
    s[t] = v;
    __syncthreads();
    for (int off = 128; off > 0; off >>= 1) {
        if (t < off) s[t] += s[t + off];
        __syncthreads();
    }
    if (t == 0) bsum[blockIdx.x] = s[0];
}

// S2: exclusive scan of the 256 block sums
__global__ __launch_bounds__(256) void scan_offsets_kernel(const int* __restrict__ bsum,
                                                           int* __restrict__ boff,
                                                           int* __restrict__ row_ptr, int n) {
    __shared__ int s[256];
    int t = threadIdx.x;
    int v = bsum[t];
    s[t] = v;
    __syncthreads();
    for (int off = 1; off < 256; off <<= 1) {
        int tmp = (t >= off) ? s[t - off] : 0;
        __syncthreads();
        s[t] += tmp;
        __syncthreads();
    }
    boff[t] = s[t] - v;            // exclusive
    if (t == 255) row_ptr[n] = s[255];
}

// S3: per-block exclusive scan + write row_ptr/cursor/inv_deg
__global__ __launch_bounds__(256) void scan_write_kernel(const int* __restrict__ deg,
                                                         const int* __restrict__ boff,
                                                         int* __restrict__ row_ptr,
                                                         int* __restrict__ cursor,
                                                         float* __restrict__ inv_deg, int n) {
    __shared__ int s[256];
    int t = threadIdx.x;
    int i = blockIdx.x * 256 + t;
    int v = (i < n) ? deg[i] : 0;
    s[t] = v;
    __syncthreads();
    for (int off = 1; off < 256; off <<= 1) {
        int tmp = (t >= off) ? s[t - off] : 0;
        __syncthreads();
        s[t] += tmp;
        __syncthreads();
    }
    if (i < n) {
        int excl = s[t] - v + boff[blockIdx.x];
        row_ptr[i] = excl;
        cursor[i] = excl;
        inv_deg[i] = 1.0f / (float)max(v, 1);
    }
}

__global__ void fill_csr_kernel(const int* __restrict__ src, const int* __restrict__ dst,
                                int* __restrict__ cursor, int* __restrict__ col, int E) {
    int e = blockIdx.x * blockDim.x + threadIdx.x;
    if (e < E) {
        int pos = atomicAdd(&cursor[dst[e]], 1);
        col[pos] = src[e];
    }
}

// agg[v] = inv_deg[v] * sum_{u in N(v)} h[u]   (h is [n, 128] fp32)
// One wave (64 lanes, float2/lane) per node. col loaded cooperatively
// (coalesced, 64 at a time) and broadcast via shfl; gathers unrolled x4.
__global__ __launch_bounds__(256) void aggregate_kernel(const float* __restrict__ h,
                                                        const int* __restrict__ row_ptr,
                                                        const int* __restrict__ col,
                                                        const float* __restrict__ inv_deg,
                                                        float* __restrict__ agg, int n) {
    int wave = threadIdx.x >> 6;
    int lane = threadIdx.x & 63;
    int node = blockIdx.x * 4 + wave;
    if (node >= n) return;
    int beg = row_ptr[node];
    int end = row_ptr[node + 1];
    const int coloff = lane << 1;
    float2 acc = make_float2(0.f, 0.f);
    for (int base = beg; base < end; base += 64) {
        int m = end - base;
        if (m > 64) m = 64;
        int myc = (lane < m) ? col[base + lane] : 0;
        int j = 0;
        for (; j + 4 <= m; j += 4) {
            int u0 = __shfl(myc, j + 0);
            int u1 = __shfl(myc, j + 1);
            int u2 = __shfl(myc, j + 2);
            int u3 = __shfl(myc, j + 3);
            float2 v0 = *(const float2*)&h[(size_t)u0 * D_H + coloff];
            float2 v1 = *(const float2*)&h[(size_t)u1 * D_H + coloff];
            float2 v2 = *(const float2*)&h[(size_t)u2 * D_H + coloff];
            float2 v3 = *(const float2*)&h[(size_t)u3 * D_H + coloff];
            acc.x += v0.x + v1.x + v2.x + v3.x;
            acc.y += v0.y + v1.y + v2.y + v3.y;
        }
        for (; j < m; ++j) {
            int u = __shfl(myc, j);
            float2 v = *(const float2*)&h[(size_t)u * D_H + coloff];
            acc.x += v.x;
            acc.y += v.y;
        }
    }
    float s = inv_deg[node];
    float2 o = make_float2(acc.x * s, acc.y * s);
    *(float2*)&agg[(size_t)node * D_H + coloff] = o;
}

// out[n,o] = relu?( sum_k Xa[n,k]*Wa[o,k] + sum_k Xh[n,k]*Wh[o,k] + bias[o] )
#define BM 64
#define BN 64
#define KC 64
__global__ __launch_bounds__(256) void gemm_sage_kernel(
        const float* __restrict__ Xa, const float* __restrict__ Xh,
        const float* __restrict__ Wa, const float* __restrict__ Wh,
        const float* __restrict__ bias, float* __restrict__ out,
        int N, int K1, int Do, int do_relu) {
    __shared__ float Xs[KC][BM + 4];
    __shared__ float Ws[KC][BN + 4];
    const int tid = threadIdx.x;
    const int tx = tid & 15, ty = tid >> 4;
    const int m0 = ty << 2, n0 = tx << 2;
    const int row0 = blockIdx.x * BM;
    const int col0 = blockIdx.y * BN;
    float acc[4][4] = {};

    for (int half = 0; half < 2; ++half) {
        const float* __restrict__ X = half ? Xh : Xa;
        const float* __restrict__ W = half ? Wh : Wa;
        for (int kc = 0; kc < K1; kc += KC) {
            __syncthreads();
            #pragma unroll
            for (int q = tid; q < BM * KC / 4; q += 256) {
                int r = q >> 4;
                int k4 = (q & 15) << 2;
                float4 v = make_float4(0.f, 0.f, 0.f, 0.f);
                int row = row0 + r;
                if (row < N) v = *(const float4*)&X[(size_t)row * K1 + kc + k4];
                Xs[k4 + 0][r] = v.x; Xs[k4 + 1][r] = v.y;
                Xs[k4 + 2][r] = v.z; Xs[k4 + 3][r] = v.w;
            }
            #pragma unroll
            for (int q = tid; q < BN * KC / 4; q += 256) {
                int r = q >> 4;
                int k4 = (q & 15) << 2;
                float4 v = *(const float4*)&W[(size_t)(col0 + r) * K1 + kc + k4];
                Ws[k4 + 0][r] = v.x; Ws[k4 + 1][r] = v.y;
                Ws[k4 + 2][r] = v.z; Ws[k4 + 3][r] = v.w;
            }
            __syncthreads();
            #pragma unroll 8
            for (int k = 0; k < KC; ++k) {
                float4 a = *(const float4*)&Xs[k][m0];
                float4 b = *(const float4*)&Ws[k][n0];
                acc[0][0] += a.x * b.x; acc[0][1] += a.x * b.y; acc[0][2] += a.x * b.z; acc[0][3] += a.x * b.w;
                acc[1][0] += a.y * b.x; acc[1][1] += a.y * b.y; acc[1][2] += a.y * b.z; acc[1][3] += a.y * b.w;
                acc[2][0] += a.z * b.x; acc[2][1] += a.z * b.y; acc[2][2] += a.z * b.z; acc[2][3] += a.z * b.w;
                acc[3][0] += a.w * b.x; acc[3][1] += a.w * b.y; acc[3][2] += a.w * b.z; acc[3][3] += a.w * b.w;
            }
        }
    }

    #pragma unroll
    for (int i = 0; i < 4; ++i) {
        int r = row0 + m0 + i;
        if (r >= N) continue;
        int c0 = col0 + n0;
        float4 v;
        v.x = acc[i][0] + bias[c0 + 0];
        v.y = acc[i][1] + bias[c0 + 1];
        v.z = acc[i][2] + bias[c0 + 2];
        v.w = acc[i][3] + bias[c0 + 3];
        if (do_relu) {
            v.x = fmaxf(v.x, 0.f); v.y = fmaxf(v.y, 0.f);
            v.z = fmaxf(v.z, 0.f); v.w = fmaxf(v.w, 0.f);
        }
        *(float4*)&out[(size_t)r * Do + c0] = v;
    }
}

extern "C" void kernel_launch(void* const* d_in, const int* in_sizes, int n_in,
                              void* d_out, int out_size, void* d_ws, size_t ws_size,
                              hipStream_t stream) {
    const float* x   = (const float*)d_in[0];
    const int*   edge = (const int*)d_in[1];   // int32: [2, E]
    const float* Wl0 = (const float*)d_in[2];
    const float* bl0 = (const float*)d_in[3];
    const float* Wr0 = (const float*)d_in[4];
    const float* Wl1 = (const float*)d_in[5];
    const float* bl1 = (const float*)d_in[6];
    const float* Wr1 = (const float*)d_in[7];
    const float* Wl2 = (const float*)d_in[8];
    const float* bl2 = (const float*)d_in[9];
    const float* Wr2 = (const float*)d_in[10];
    float* out = (float*)d_out;

    const int N = in_sizes[0] / D_H;   // 50000
    const int E = in_sizes[1] / 2;     // 800000
    const int* src = edge;
    const int* dst = edge + E;

    char* w = (char*)d_ws;
    float* agg = (float*)w;      w += (size_t)N * D_H * 4;
    float* A   = (float*)w;      w += (size_t)N * D_H * 4;
    float* B   = (float*)w;      w += (size_t)N * D_H * 4;
    int* deg     = (int*)w;      w += (size_t)N * 4;
    int* row_ptr = (int*)w;      w += (size_t)(N + 1) * 4;
    int* cursor  = (int*)w;      w += (size_t)N * 4;
    float* inv_deg = (float*)w;  w += (size_t)N * 4;
    int* bsum    = (int*)w;      w += (size_t)NB_SCAN * 4;
    int* boff    = (int*)w;      w += (size_t)NB_SCAN * 4;
    int* col     = (int*)w;      w += (size_t)E * 4;

    // ---- CSR build ----
    hipMemsetAsync(deg, 0, (size_t)N * 4, stream);
    count_deg_kernel<<<(E + 255) / 256, 256, 0, stream>>>(dst, deg, E);
    scan_reduce_kernel<<<NB_SCAN, 256, 0, stream>>>(deg, bsum, N);
    scan_offsets_kernel<<<1, 256, 0, stream>>>(bsum, boff, row_ptr, N);
    scan_write_kernel<<<NB_SCAN, 256, 0, stream>>>(deg, boff, row_ptr, cursor, inv_deg, N);
    fill_csr_kernel<<<(E + 255) / 256, 256, 0, stream>>>(src, dst, cursor, col, E);

    const int gx = (N + BM - 1) / BM;
    const int agg_grid = (N + 3) / 4;

    // ---- layer 0: x -> A (relu) ----
    aggregate_kernel<<<agg_grid, 256, 0, stream>>>(x, row_ptr, col, inv_deg, agg, N);
    gemm_sage_kernel<<<dim3(gx, 2), 256, 0, stream>>>(agg, x, Wl0, Wr0, bl0, A, N, 128, 128, 1);

    // ---- layer 1: A -> B (relu) ----
    aggregate_kernel<<<agg_grid, 256, 0, stream>>>(A, row_ptr, col, inv_deg, agg, N);
    gemm_sage_kernel<<<dim3(gx, 2), 256, 0, stream>>>(agg, A, Wl1, Wr1, bl1, B, N, 128, 128, 1);

    // ---- layer 2: B -> out (no relu) ----
    aggregate_kernel<<<agg_grid, 256, 0, stream>>>(B, row_ptr, col, inv_deg, agg, N);
    gemm_sage_kernel<<<dim3(gx, 1), 256, 0, stream>>>(agg, B, Wl2, Wr2, bl2, out, N, 128, 64, 0);
}